// Round 5
// baseline (379.566 us; speedup 1.0000x reference)
//
#include <hip/hip_runtime.h>
#include <hip/hip_bf16.h>

typedef unsigned short ushort_t;
typedef __attribute__((ext_vector_type(8))) short short8;
typedef __attribute__((ext_vector_type(4))) short short4v;
typedef __attribute__((ext_vector_type(4))) float floatx4;

#define MFMA16(a, b, c) __builtin_amdgcn_mfma_f32_16x16x32_bf16(a, b, c, 0, 0, 0)

__device__ __forceinline__ float bf2f(ushort_t u) {
    unsigned int v = ((unsigned int)u) << 16;
    return __int_as_float((int)v);
}
__device__ __forceinline__ ushort_t f2bf(float f) {
    unsigned int x = (unsigned int)__float_as_int(f);
    unsigned int r = (x + 0x7FFFu + ((x >> 16) & 1u)) >> 16;
    return (ushort_t)r;
}

// ---------------------------------------------------------------- fp32 -> bf16 convert
__global__ __launch_bounds__(256) void k_cvt(const floatx4* __restrict__ src,
                                             short4v* __restrict__ dst, int n4) {
    int i = blockIdx.x * 256 + threadIdx.x;
    if (i < n4) {
        floatx4 v = src[i];
        short4v o;
        o[0] = (short)f2bf(v[0]);
        o[1] = (short)f2bf(v[1]);
        o[2] = (short)f2bf(v[2]);
        o[3] = (short)f2bf(v[3]);
        dst[i] = o;
    }
}

// ---------------------------------------------------------------- fp32 transpose -> bf16
__global__ __launch_bounds__(256) void k_transpose_cvt(const float* __restrict__ src,
                                                       ushort_t* __restrict__ dst, int R, int C) {
    __shared__ float t[32][33];
    int tx = threadIdx.x & 31, ty = threadIdx.x >> 5;
    int r0 = blockIdx.y * 32, c0 = blockIdx.x * 32;
    for (int y = ty; y < 32; y += 8) t[y][tx] = src[(r0 + y) * C + c0 + tx];
    __syncthreads();
    for (int y = ty; y < 32; y += 8) dst[(c0 + y) * R + r0 + tx] = f2bf(t[tx][y]);
}

// ---------------------------------------------------------------- K1: qkv = x @ w_qkv, scatter q/k/vT
__global__ __launch_bounds__(256) void k_qkv(const ushort_t* __restrict__ x,
                                             const ushort_t* __restrict__ wt,
                                             ushort_t* __restrict__ qs,
                                             ushort_t* __restrict__ ks,
                                             ushort_t* __restrict__ vt) {
    __shared__ __align__(16) ushort_t st[64 * 72];
    const int tid = threadIdx.x, lane = tid & 63, wv = tid >> 6;
    const int col = lane & 15, quad = lane >> 4;
    const int row0 = blockIdx.y * 64 + (wv >> 1) * 32;
    const int c0 = blockIdx.x * 64 + (wv & 1) * 32;
    const int which = blockIdx.x >> 3, hh = blockIdx.x & 7;
    const int brow0 = blockIdx.y * 64;
    const int bb = brow0 >> 11, n0 = brow0 & 2047;
    const int hidx = bb * 8 + hh;
    floatx4 acc[2][2];
#pragma unroll
    for (int i = 0; i < 2; i++)
#pragma unroll
        for (int j = 0; j < 2; j++) acc[i][j] = (floatx4){0.f, 0.f, 0.f, 0.f};
    for (int k0 = 0; k0 < 512; k0 += 32) {
        const int ko = k0 + quad * 8;
        short8 a0 = *(const short8*)&x[(row0 + col) * 512 + ko];
        short8 a1 = *(const short8*)&x[(row0 + 16 + col) * 512 + ko];
        short8 b0 = *(const short8*)&wt[(c0 + col) * 512 + ko];
        short8 b1 = *(const short8*)&wt[(c0 + 16 + col) * 512 + ko];
        acc[0][0] = MFMA16(a0, b0, acc[0][0]);
        acc[0][1] = MFMA16(a0, b1, acc[0][1]);
        acc[1][0] = MFMA16(a1, b0, acc[1][0]);
        acc[1][1] = MFMA16(a1, b1, acc[1][1]);
    }
    const float qscale = (which == 0) ? 0.125f : 1.0f;  // fold SCALE into q
#pragma unroll
    for (int i = 0; i < 2; i++)
#pragma unroll
        for (int j = 0; j < 2; j++)
#pragma unroll
            for (int r = 0; r < 4; r++) {
                int il = (wv >> 1) * 32 + i * 16 + quad * 4 + r;
                int cl = (wv & 1) * 32 + j * 16 + col;
                ushort_t hv = f2bf(acc[i][j][r] * qscale);
                if (which == 2) st[cl * 72 + il] = hv;   // transposed: [d][n]
                else            st[il * 72 + cl] = hv;   // [n][d]
            }
    __syncthreads();
    if (which < 2) {
        ushort_t* dst = (which == 0) ? qs : ks;
#pragma unroll
        for (int s = tid; s < 512; s += 256) {
            int rr = s >> 3, dc = (s & 7) * 8;
            *(short8*)&dst[(hidx * 2048 + n0 + rr) * 64 + dc] = *(const short8*)&st[rr * 72 + dc];
        }
    } else {
#pragma unroll
        for (int s = tid; s < 512; s += 256) {
            int d = s >> 3, nc = (s & 7) * 8;
            *(short8*)&vt[(hidx * 64 + d) * 2048 + n0 + nc] = *(const short8*)&st[d * 72 + nc];
        }
    }
}

// ---------------------------------------------------------------- K2a: l_g[i] partials
// grid (jc=4, i=128, b=2), 256 thr (4 waves). No max-shift: exp(s) safe in fp32.
__global__ __launch_bounds__(256, 4) void k_stats(const ushort_t* __restrict__ qs,
                                                  const ushort_t* __restrict__ ks,
                                                  const float* __restrict__ w_pre,
                                                  float* __restrict__ lpart) {
    __shared__ __align__(16) ushort_t qlds[8 * 16 * 72];
    __shared__ float lred[4][8][16];
    const int tid = threadIdx.x, lane = tid & 63, wv = tid >> 6;
    const int col = lane & 15, quad = lane >> 4;
    const int jc = blockIdx.x, b = blockIdx.z, n0 = blockIdx.y * 16;
    for (int c = tid; c < 1024; c += 256) {
        int hh = c >> 7, rem = c & 127, ii = rem >> 3, dc = (rem & 7) * 8;
        *(short8*)&qlds[(hh * 16 + ii) * 72 + dc] =
            *(const short8*)&qs[((b * 8 + hh) * 2048 + n0 + ii) * 64 + dc];
    }
    __syncthreads();
    float Lacc[8][4];
#pragma unroll
    for (int g = 0; g < 8; g++)
#pragma unroll
        for (int r = 0; r < 4; r++) Lacc[g][r] = 0.f;
    for (int it = 0; it < 8; it++) {
        const int jw = jc * 512 + it * 64 + wv * 16;
        floatx4 S[8];
#pragma unroll
        for (int h = 0; h < 8; h++) {
            const ushort_t* qb = &qlds[(h * 16 + col) * 72 + quad * 8];
            short8 a0 = *(const short8*)&qb[0];
            short8 a1 = *(const short8*)&qb[32];
            const ushort_t* kb = &ks[((b * 8 + h) * 2048 + jw + col) * 64 + quad * 8];
            short8 b0 = *(const short8*)&kb[0];
            short8 b1 = *(const short8*)&kb[32];
            floatx4 a = (floatx4){0.f, 0.f, 0.f, 0.f};
            a = MFMA16(a0, b0, a);
            a = MFMA16(a1, b1, a);
            S[h] = a;
        }
#pragma unroll
        for (int g = 0; g < 8; g++)
#pragma unroll
            for (int r = 0; r < 4; r++) {
                float s = 0.f;
#pragma unroll
                for (int h = 0; h < 8; h++) s = fmaf(w_pre[g * 8 + h], S[h][r], s);
                Lacc[g][r] += __expf(s);
            }
    }
#pragma unroll
    for (int g = 0; g < 8; g++)
#pragma unroll
        for (int r = 0; r < 4; r++) {
            float v = Lacc[g][r];
            v += __shfl_xor(v, 1, 64);
            v += __shfl_xor(v, 2, 64);
            v += __shfl_xor(v, 4, 64);
            v += __shfl_xor(v, 8, 64);
            if (col == 0) lred[wv][g][quad * 4 + r] = v;
        }
    __syncthreads();
    if (tid < 128) {
        int g = tid >> 4, ii = tid & 15;
        float l = lred[0][g][ii] + lred[1][g][ii] + lred[2][g][ii] + lred[3][g][ii];
        lpart[((b * 4 + jc) * 8 + g) * 2048 + n0 + ii] = l;
    }
}

// ---------------------------------------------------------------- K2b: single-pass attention
// linv known -> postmix inside j-loop -> ONE accumulator per wave (no spills).
__global__ __launch_bounds__(512, 2) void k_attn(const ushort_t* __restrict__ qs,
                                                 const ushort_t* __restrict__ ks,
                                                 const ushort_t* __restrict__ vt,
                                                 const float* __restrict__ w_pre,
                                                 const float* __restrict__ w_post,
                                                 const float* __restrict__ lpart,
                                                 const ushort_t* __restrict__ wot,
                                                 const float* __restrict__ bias,
                                                 float* __restrict__ out) {
    __shared__ __align__(16) ushort_t qlds[8 * 16 * 72];   // 18 KB
    __shared__ __align__(16) ushort_t amix[8 * 16 * 136];  // 35 KB post-mix P, A-layout
    __shared__ __align__(16) ushort_t oline[16 * 520];     // 16.6 KB attn-out rows
    __shared__ float linv[8][16];
    const int tid = threadIdx.x, lane = tid & 63, wv = tid >> 6;
    const int col = lane & 15, quad = lane >> 4;
    const int b = blockIdx.y, n0 = blockIdx.x * 16;
    const int e = wv;  // wave's output head

    for (int c = tid; c < 1024; c += 512) {
        int hh = c >> 7, rem = c & 127, ii = rem >> 3, dc = (rem & 7) * 8;
        *(short8*)&qlds[(hh * 16 + ii) * 72 + dc] =
            *(const short8*)&qs[((b * 8 + hh) * 2048 + n0 + ii) * 64 + dc];
    }
    if (tid < 128) {
        int g = tid >> 4, ii = tid & 15;
        float l = 0.f;
#pragma unroll
        for (int jc = 0; jc < 4; jc++) l += lpart[((b * 4 + jc) * 8 + g) * 2048 + n0 + ii];
        linv[g][ii] = 1.0f / l;
    }
    __syncthreads();
    float lr[8][4];
#pragma unroll
    for (int g = 0; g < 8; g++)
#pragma unroll
        for (int r = 0; r < 4; r++) lr[g][r] = linv[g][quad * 4 + r];

    floatx4 O[4];
#pragma unroll
    for (int nt = 0; nt < 4; nt++) O[nt] = (floatx4){0.f, 0.f, 0.f, 0.f};

    for (int jt = 0; jt < 16; jt++) {
        const int j0 = jt * 128;
        const int jw = j0 + wv * 16;
        floatx4 S[8];
#pragma unroll
        for (int h = 0; h < 8; h++) {
            const ushort_t* qb = &qlds[(h * 16 + col) * 72 + quad * 8];
            short8 a0 = *(const short8*)&qb[0];
            short8 a1 = *(const short8*)&qb[32];
            const ushort_t* kb = &ks[((b * 8 + h) * 2048 + jw + col) * 64 + quad * 8];
            short8 b0 = *(const short8*)&kb[0];
            short8 b1 = *(const short8*)&kb[32];
            floatx4 a = (floatx4){0.f, 0.f, 0.f, 0.f};
            a = MFMA16(a0, b0, a);
            a = MFMA16(a1, b1, a);
            S[h] = a;
        }
        // premix (SGPR weights) + exp*linv
        float P[8][4];
#pragma unroll
        for (int g = 0; g < 8; g++)
#pragma unroll
            for (int r = 0; r < 4; r++) {
                float s = 0.f;
#pragma unroll
                for (int h = 0; h < 8; h++) s = fmaf(w_pre[g * 8 + h], S[h][r], s);
                P[g][r] = __expf(s) * lr[g][r];
            }
        // postmix (SGPR weights) -> amix LDS (A-operand layout)
#pragma unroll
        for (int e2 = 0; e2 < 8; e2++)
#pragma unroll
            for (int r = 0; r < 4; r++) {
                float a = 0.f;
#pragma unroll
                for (int g = 0; g < 8; g++) a = fmaf(w_post[e2 * 8 + g], P[g][r], a);
                amix[(e2 * 16 + quad * 4 + r) * 136 + wv * 16 + col] = f2bf(a);
            }
        __syncthreads();
#pragma unroll
        for (int nt = 0; nt < 4; nt++) {
            floatx4 a = O[nt];
#pragma unroll
            for (int k2 = 0; k2 < 4; k2++) {
                short8 af = *(const short8*)&amix[(e * 16 + col) * 136 + k2 * 32 + quad * 8];
                short8 bf = *(const short8*)&vt[((b * 8 + e) * 64 + nt * 16 + col) * 2048 + j0 +
                                                k2 * 32 + quad * 8];
                a = MFMA16(af, bf, a);
            }
            O[nt] = a;
        }
        __syncthreads();
    }
    // ---- stage attention-out rows (16 x 512)
#pragma unroll
    for (int nt = 0; nt < 4; nt++)
#pragma unroll
        for (int r = 0; r < 4; r++)
            oline[(quad * 4 + r) * 520 + e * 64 + nt * 16 + col] = f2bf(O[nt][r]);
    __syncthreads();
    // ---- fused output projection
#pragma unroll
    for (int nt = 0; nt < 4; nt++) {
        floatx4 acc = (floatx4){0.f, 0.f, 0.f, 0.f};
        const int c = wv * 64 + nt * 16 + col;
#pragma unroll
        for (int k2 = 0; k2 < 16; k2++) {
            short8 af = *(const short8*)&oline[col * 520 + k2 * 32 + quad * 8];
            short8 bf = *(const short8*)&wot[c * 512 + k2 * 32 + quad * 8];
            acc = MFMA16(af, bf, acc);
        }
        float bz = bias[c];
#pragma unroll
        for (int r = 0; r < 4; r++)
            out[(b * 2048 + n0 + quad * 4 + r) * 512 + c] = acc[r] + bz;
    }
}

// ---------------------------------------------------------------- launch
extern "C" void kernel_launch(void* const* d_in, const int* in_sizes, int n_in,
                              void* d_out, int out_size, void* d_ws, size_t ws_size,
                              hipStream_t stream) {
    const float* x = (const float*)d_in[0];
    const float* w_qkv = (const float*)d_in[1];
    const float* w_pre = (const float*)d_in[2];
    const float* w_post = (const float*)d_in[3];
    const float* w_out = (const float*)d_in[4];
    const float* b_out = (const float*)d_in[5];
    char* ws = (char*)d_ws;
    ushort_t* qs = (ushort_t*)(ws);                            // 4 MB  [b,h,n,d] (pre-scaled)
    ushort_t* ks = (ushort_t*)(ws + (4u << 20));               // 4 MB  [b,h,n,d]
    ushort_t* vt = (ushort_t*)(ws + (8u << 20));               // 4 MB  [b,h,d,n]
    ushort_t* xb = (ushort_t*)(ws + (12u << 20));              // 4 MB  x in bf16
    ushort_t* wt = (ushort_t*)(ws + (16u << 20));              // 1.5 MB w_qkv^T bf16
    ushort_t* wot = (ushort_t*)(ws + (16u << 20) + 1572864u);  // 0.5 MB w_out^T bf16
    float* lpart = (float*)(ws + (18u << 20));                 // 512 KB l partials
    float* out = (float*)d_out;

    k_cvt<<<dim3(2048), dim3(256), 0, stream>>>((const floatx4*)x, (short4v*)xb, 524288);
    k_transpose_cvt<<<dim3(48, 16), dim3(256), 0, stream>>>(w_qkv, wt, 512, 1536);
    k_transpose_cvt<<<dim3(16, 16), dim3(256), 0, stream>>>(w_out, wot, 512, 512);
    k_qkv<<<dim3(24, 64), dim3(256), 0, stream>>>(xb, wt, qs, ks, vt);
    k_stats<<<dim3(4, 128, 2), dim3(256), 0, stream>>>(qs, ks, w_pre, lpart);
    k_attn<<<dim3(128, 2), dim3(512), 0, stream>>>(qs, ks, vt, w_pre, w_post, lpart, wot, b_out, out);
}

// Round 6
// 374.304 us; speedup vs baseline: 1.0141x; 1.0141x over previous
//
#include <hip/hip_runtime.h>
#include <hip/hip_bf16.h>

typedef unsigned short ushort_t;
typedef __attribute__((ext_vector_type(8))) short short8;
typedef __attribute__((ext_vector_type(4))) short short4v;
typedef __attribute__((ext_vector_type(4))) float floatx4;
typedef __attribute__((ext_vector_type(2))) float floatx2;

#define MFMA16(a, b, c) __builtin_amdgcn_mfma_f32_16x16x32_bf16(a, b, c, 0, 0, 0)

__device__ __forceinline__ float bf2f(ushort_t u) {
    unsigned int v = ((unsigned int)u) << 16;
    return __int_as_float((int)v);
}
__device__ __forceinline__ ushort_t f2bf(float f) {
    unsigned int x = (unsigned int)__float_as_int(f);
    unsigned int r = (x + 0x7FFFu + ((x >> 16) & 1u)) >> 16;
    return (ushort_t)r;
}

// ---------------------------------------------------------------- fp32 -> bf16 convert
__global__ __launch_bounds__(256) void k_cvt(const floatx4* __restrict__ src,
                                             short4v* __restrict__ dst, int n4) {
    int i = blockIdx.x * 256 + threadIdx.x;
    if (i < n4) {
        floatx4 v = src[i];
        short4v o;
        o[0] = (short)f2bf(v[0]);
        o[1] = (short)f2bf(v[1]);
        o[2] = (short)f2bf(v[2]);
        o[3] = (short)f2bf(v[3]);
        dst[i] = o;
    }
}

// ---------------------------------------------------------------- fp32 transpose -> bf16
__global__ __launch_bounds__(256) void k_transpose_cvt(const float* __restrict__ src,
                                                       ushort_t* __restrict__ dst, int R, int C) {
    __shared__ float t[32][33];
    int tx = threadIdx.x & 31, ty = threadIdx.x >> 5;
    int r0 = blockIdx.y * 32, c0 = blockIdx.x * 32;
    for (int y = ty; y < 32; y += 8) t[y][tx] = src[(r0 + y) * C + c0 + tx];
    __syncthreads();
    for (int y = ty; y < 32; y += 8) dst[(c0 + y) * R + r0 + tx] = f2bf(t[tx][y]);
}

// ---------------------------------------------------------------- K1: qkv = x @ w_qkv
// 128n x 64c blocks: wave = 32 rows x 64 cols (2x4 frags, 8 MFMA per 6 loads).
__global__ __launch_bounds__(256, 3) void k_qkv(const ushort_t* __restrict__ x,
                                                const ushort_t* __restrict__ wt,
                                                ushort_t* __restrict__ qs,
                                                ushort_t* __restrict__ ks,
                                                ushort_t* __restrict__ vt) {
    __shared__ __align__(16) ushort_t st[9216];  // 128*72 (q/k) or 64*136 (vT)
    const int tid = threadIdx.x, lane = tid & 63, wv = tid >> 6;
    const int col = lane & 15, quad = lane >> 4;
    const int which = blockIdx.x >> 3, hh = blockIdx.x & 7;
    const int c0 = blockIdx.x * 64;
    const int absrow0 = blockIdx.y * 128;
    const int bb = blockIdx.y >> 4, n0 = (blockIdx.y & 15) * 128;
    const int hidx = bb * 8 + hh;
    const int row0 = absrow0 + wv * 32;
    floatx4 acc[2][4];
#pragma unroll
    for (int i = 0; i < 2; i++)
#pragma unroll
        for (int j = 0; j < 4; j++) acc[i][j] = (floatx4){0.f, 0.f, 0.f, 0.f};
    for (int k0 = 0; k0 < 512; k0 += 32) {
        const int ko = k0 + quad * 8;
        short8 a0 = *(const short8*)&x[(row0 + col) * 512 + ko];
        short8 a1 = *(const short8*)&x[(row0 + 16 + col) * 512 + ko];
        short8 b0 = *(const short8*)&wt[(c0 + col) * 512 + ko];
        short8 b1 = *(const short8*)&wt[(c0 + 16 + col) * 512 + ko];
        short8 b2 = *(const short8*)&wt[(c0 + 32 + col) * 512 + ko];
        short8 b3 = *(const short8*)&wt[(c0 + 48 + col) * 512 + ko];
        acc[0][0] = MFMA16(a0, b0, acc[0][0]);
        acc[0][1] = MFMA16(a0, b1, acc[0][1]);
        acc[0][2] = MFMA16(a0, b2, acc[0][2]);
        acc[0][3] = MFMA16(a0, b3, acc[0][3]);
        acc[1][0] = MFMA16(a1, b0, acc[1][0]);
        acc[1][1] = MFMA16(a1, b1, acc[1][1]);
        acc[1][2] = MFMA16(a1, b2, acc[1][2]);
        acc[1][3] = MFMA16(a1, b3, acc[1][3]);
    }
    const float qscale = (which == 0) ? 0.125f : 1.0f;  // fold SCALE into q
#pragma unroll
    for (int i = 0; i < 2; i++)
#pragma unroll
        for (int j = 0; j < 4; j++)
#pragma unroll
            for (int r = 0; r < 4; r++) {
                int il = wv * 32 + i * 16 + quad * 4 + r;  // 0..127
                int cl = j * 16 + col;                     // 0..63
                ushort_t hv = f2bf(acc[i][j][r] * qscale);
                if (which == 2) st[cl * 136 + il] = hv;  // transposed: [d][n]
                else            st[il * 72 + cl] = hv;   // [n][d]
            }
    __syncthreads();
    if (which < 2) {
        ushort_t* dst = (which == 0) ? qs : ks;
#pragma unroll
        for (int s = tid; s < 1024; s += 256) {
            int rr = s >> 3, dc = (s & 7) * 8;
            *(short8*)&dst[(hidx * 2048 + n0 + rr) * 64 + dc] = *(const short8*)&st[rr * 72 + dc];
        }
    } else {
#pragma unroll
        for (int s = tid; s < 1024; s += 256) {
            int d = s >> 4, nc = (s & 15) * 8;
            *(short8*)&vt[(hidx * 64 + d) * 2048 + n0 + nc] = *(const short8*)&st[d * 136 + nc];
        }
    }
}

// ---------------------------------------------------------------- K2a: l_g[i] partials
__global__ __launch_bounds__(256, 4) void k_stats(const ushort_t* __restrict__ qs,
                                                  const ushort_t* __restrict__ ks,
                                                  const float* __restrict__ w_pre,
                                                  float* __restrict__ lpart) {
    __shared__ __align__(16) ushort_t qlds[8 * 16 * 72];
    __shared__ float lred[4][8][16];
    const int tid = threadIdx.x, lane = tid & 63, wv = tid >> 6;
    const int col = lane & 15, quad = lane >> 4;
    const int jc = blockIdx.x, b = blockIdx.z, n0 = blockIdx.y * 16;
    for (int c = tid; c < 1024; c += 256) {
        int hh = c >> 7, rem = c & 127, ii = rem >> 3, dc = (rem & 7) * 8;
        *(short8*)&qlds[(hh * 16 + ii) * 72 + dc] =
            *(const short8*)&qs[((b * 8 + hh) * 2048 + n0 + ii) * 64 + dc];
    }
    __syncthreads();
    floatx2 Lacc[8][2];
#pragma unroll
    for (int g = 0; g < 8; g++)
#pragma unroll
        for (int r2 = 0; r2 < 2; r2++) Lacc[g][r2] = (floatx2){0.f, 0.f};
    for (int it = 0; it < 8; it++) {
        const int jw = jc * 512 + it * 64 + wv * 16;
        floatx4 S[8];
#pragma unroll
        for (int h = 0; h < 8; h++) {
            const ushort_t* qb = &qlds[(h * 16 + col) * 72 + quad * 8];
            short8 a0 = *(const short8*)&qb[0];
            short8 a1 = *(const short8*)&qb[32];
            const ushort_t* kb = &ks[((b * 8 + h) * 2048 + jw + col) * 64 + quad * 8];
            short8 b0 = *(const short8*)&kb[0];
            short8 b1 = *(const short8*)&kb[32];
            floatx4 a = (floatx4){0.f, 0.f, 0.f, 0.f};
            a = MFMA16(a0, b0, a);
            a = MFMA16(a1, b1, a);
            S[h] = a;
        }
#pragma unroll
        for (int g = 0; g < 8; g++)
#pragma unroll
            for (int r2 = 0; r2 < 2; r2++) {
                floatx2 s = (floatx2){0.f, 0.f};
#pragma unroll
                for (int h = 0; h < 8; h++) {
                    floatx2 sv = (floatx2){S[h][2 * r2], S[h][2 * r2 + 1]};
                    s += sv * w_pre[g * 8 + h];  // v_pk_fma_f32
                }
                Lacc[g][r2] += (floatx2){__expf(s.x), __expf(s.y)};
            }
    }
#pragma unroll
    for (int g = 0; g < 8; g++)
#pragma unroll
        for (int r = 0; r < 4; r++) {
            float v = (r & 1) ? Lacc[g][r >> 1].y : Lacc[g][r >> 1].x;
            v += __shfl_xor(v, 1, 64);
            v += __shfl_xor(v, 2, 64);
            v += __shfl_xor(v, 4, 64);
            v += __shfl_xor(v, 8, 64);
            if (col == 0) lred[wv][g][quad * 4 + r] = v;
        }
    __syncthreads();
    if (tid < 128) {
        int g = tid >> 4, ii = tid & 15;
        float l = lred[0][g][ii] + lred[1][g][ii] + lred[2][g][ii] + lred[3][g][ii];
        lpart[((b * 4 + jc) * 8 + g) * 2048 + n0 + ii] = l;
    }
}

// ---------------------------------------------------------------- K2b: j-split attention
// grid (jc=4, it=128, b=2). Each block: its j-quarter, postmix in-loop, partial O,
// partial projection, atomicAdd into pre-zeroed out. Projection is linear in O.
__global__ __launch_bounds__(512, 4) void k_attn(const ushort_t* __restrict__ qs,
                                                 const ushort_t* __restrict__ ks,
                                                 const ushort_t* __restrict__ vt,
                                                 const float* __restrict__ w_pre,
                                                 const float* __restrict__ w_post,
                                                 const float* __restrict__ lpart,
                                                 const ushort_t* __restrict__ wot,
                                                 const float* __restrict__ bias,
                                                 float* __restrict__ out) {
    __shared__ __align__(16) ushort_t qlds[8 * 16 * 72];   // 18.4 KB
    __shared__ __align__(16) ushort_t amix[8 * 16 * 136];  // 34.8 KB (aliased as oline later)
    __shared__ float linv[8][16];
    const int tid = threadIdx.x, lane = tid & 63, wv = tid >> 6;
    const int col = lane & 15, quad = lane >> 4;
    const int jc = blockIdx.x, b = blockIdx.z, n0 = blockIdx.y * 16;
    const int e = wv;  // wave's output head

    for (int c = tid; c < 1024; c += 512) {
        int hh = c >> 7, rem = c & 127, ii = rem >> 3, dc = (rem & 7) * 8;
        *(short8*)&qlds[(hh * 16 + ii) * 72 + dc] =
            *(const short8*)&qs[((b * 8 + hh) * 2048 + n0 + ii) * 64 + dc];
    }
    if (tid < 128) {
        int g = tid >> 4, ii = tid & 15;
        float l = 0.f;
#pragma unroll
        for (int q2 = 0; q2 < 4; q2++) l += lpart[((b * 4 + q2) * 8 + g) * 2048 + n0 + ii];
        linv[g][ii] = 1.0f / l;
    }
    __syncthreads();
    float lr[8][4];
#pragma unroll
    for (int g = 0; g < 8; g++)
#pragma unroll
        for (int r = 0; r < 4; r++) lr[g][r] = linv[g][quad * 4 + r];

    floatx4 O[4];
#pragma unroll
    for (int nt = 0; nt < 4; nt++) O[nt] = (floatx4){0.f, 0.f, 0.f, 0.f};

    for (int tl = 0; tl < 4; tl++) {
        const int j0 = jc * 512 + tl * 128;
        const int jw = j0 + wv * 16;
        floatx4 S[8];
#pragma unroll
        for (int h = 0; h < 8; h++) {
            const ushort_t* qb = &qlds[(h * 16 + col) * 72 + quad * 8];
            short8 a0 = *(const short8*)&qb[0];
            short8 a1 = *(const short8*)&qb[32];
            const ushort_t* kb = &ks[((b * 8 + h) * 2048 + jw + col) * 64 + quad * 8];
            short8 b0 = *(const short8*)&kb[0];
            short8 b1 = *(const short8*)&kb[32];
            floatx4 a = (floatx4){0.f, 0.f, 0.f, 0.f};
            a = MFMA16(a0, b0, a);
            a = MFMA16(a1, b1, a);
            S[h] = a;
        }
        // premix (packed fp32) + exp * linv
        floatx2 P[8][2];
#pragma unroll
        for (int g = 0; g < 8; g++)
#pragma unroll
            for (int r2 = 0; r2 < 2; r2++) {
                floatx2 s = (floatx2){0.f, 0.f};
#pragma unroll
                for (int h = 0; h < 8; h++) {
                    floatx2 sv = (floatx2){S[h][2 * r2], S[h][2 * r2 + 1]};
                    s += sv * w_pre[g * 8 + h];
                }
                P[g][r2] = (floatx2){__expf(s.x) * lr[g][2 * r2], __expf(s.y) * lr[g][2 * r2 + 1]};
            }
        // postmix (packed) -> amix (A-operand layout)
#pragma unroll
        for (int e2 = 0; e2 < 8; e2++)
#pragma unroll
            for (int r2 = 0; r2 < 2; r2++) {
                floatx2 a = (floatx2){0.f, 0.f};
#pragma unroll
                for (int g = 0; g < 8; g++) a += P[g][r2] * w_post[e2 * 8 + g];
                amix[(e2 * 16 + quad * 4 + 2 * r2) * 136 + wv * 16 + col] = f2bf(a.x);
                amix[(e2 * 16 + quad * 4 + 2 * r2 + 1) * 136 + wv * 16 + col] = f2bf(a.y);
            }
        __syncthreads();
#pragma unroll
        for (int nt = 0; nt < 4; nt++) {
            floatx4 a = O[nt];
#pragma unroll
            for (int k2 = 0; k2 < 4; k2++) {
                short8 af = *(const short8*)&amix[(e * 16 + col) * 136 + k2 * 32 + quad * 8];
                short8 bf = *(const short8*)&vt[((b * 8 + e) * 64 + nt * 16 + col) * 2048 + j0 +
                                                k2 * 32 + quad * 8];
                a = MFMA16(af, bf, a);
            }
            O[nt] = a;
        }
        __syncthreads();
    }
    // ---- stage partial attention-out rows (16 x 512), aliasing amix
    ushort_t* oline = amix;
#pragma unroll
    for (int nt = 0; nt < 4; nt++)
#pragma unroll
        for (int r = 0; r < 4; r++)
            oline[(quad * 4 + r) * 520 + e * 64 + nt * 16 + col] = f2bf(O[nt][r]);
    __syncthreads();
    // ---- partial projection + atomic accumulate
#pragma unroll
    for (int nt = 0; nt < 4; nt++) {
        floatx4 acc = (floatx4){0.f, 0.f, 0.f, 0.f};
        const int c = wv * 64 + nt * 16 + col;
#pragma unroll
        for (int k2 = 0; k2 < 16; k2++) {
            short8 af = *(const short8*)&oline[col * 520 + k2 * 32 + quad * 8];
            short8 bf = *(const short8*)&wot[c * 512 + k2 * 32 + quad * 8];
            acc = MFMA16(af, bf, acc);
        }
        float bz = (jc == 0) ? bias[c] : 0.0f;
#pragma unroll
        for (int r = 0; r < 4; r++)
            atomicAdd(&out[(b * 2048 + n0 + quad * 4 + r) * 512 + c], acc[r] + bz);
    }
}

// ---------------------------------------------------------------- launch
extern "C" void kernel_launch(void* const* d_in, const int* in_sizes, int n_in,
                              void* d_out, int out_size, void* d_ws, size_t ws_size,
                              hipStream_t stream) {
    const float* x = (const float*)d_in[0];
    const float* w_qkv = (const float*)d_in[1];
    const float* w_pre = (const float*)d_in[2];
    const float* w_post = (const float*)d_in[3];
    const float* w_out = (const float*)d_in[4];
    const float* b_out = (const float*)d_in[5];
    char* ws = (char*)d_ws;
    ushort_t* qs = (ushort_t*)(ws);                            // 4 MB  [b,h,n,d] (pre-scaled)
    ushort_t* ks = (ushort_t*)(ws + (4u << 20));               // 4 MB  [b,h,n,d]
    ushort_t* vt = (ushort_t*)(ws + (8u << 20));               // 4 MB  [b,h,d,n]
    ushort_t* xb = (ushort_t*)(ws + (12u << 20));              // 4 MB  x in bf16
    ushort_t* wt = (ushort_t*)(ws + (16u << 20));              // 1.5 MB w_qkv^T bf16
    ushort_t* wot = (ushort_t*)(ws + (16u << 20) + 1572864u);  // 0.5 MB w_out^T bf16
    float* lpart = (float*)(ws + (18u << 20));                 // 512 KB l partials
    float* out = (float*)d_out;

    hipMemsetAsync(d_out, 0, (size_t)out_size * sizeof(float), stream);
    k_cvt<<<dim3(2048), dim3(256), 0, stream>>>((const floatx4*)x, (short4v*)xb, 524288);
    k_transpose_cvt<<<dim3(48, 16), dim3(256), 0, stream>>>(w_qkv, wt, 512, 1536);
    k_transpose_cvt<<<dim3(16, 16), dim3(256), 0, stream>>>(w_out, wot, 512, 512);
    k_qkv<<<dim3(24, 32), dim3(256), 0, stream>>>(xb, wt, qs, ks, vt);
    k_stats<<<dim3(4, 128, 2), dim3(256), 0, stream>>>(qs, ks, w_pre, lpart);
    k_attn<<<dim3(4, 128, 2), dim3(512), 0, stream>>>(qs, ks, vt, w_pre, w_post, lpart, wot,
                                                      b_out, out);
}

// Round 7
// 344.865 us; speedup vs baseline: 1.1006x; 1.0854x over previous
//
#include <hip/hip_runtime.h>
#include <hip/hip_bf16.h>

typedef unsigned short ushort_t;
typedef __attribute__((ext_vector_type(8))) short short8;
typedef __attribute__((ext_vector_type(4))) short short4v;
typedef __attribute__((ext_vector_type(4))) float floatx4;
typedef __attribute__((ext_vector_type(2))) float floatx2;

#define MFMA16(a, b, c) __builtin_amdgcn_mfma_f32_16x16x32_bf16(a, b, c, 0, 0, 0)

__device__ __forceinline__ float bf2f(ushort_t u) {
    unsigned int v = ((unsigned int)u) << 16;
    return __int_as_float((int)v);
}
__device__ __forceinline__ ushort_t f2bf(float f) {
    unsigned int x = (unsigned int)__float_as_int(f);
    unsigned int r = (x + 0x7FFFu + ((x >> 16) & 1u)) >> 16;
    return (ushort_t)r;
}

// ---------------------------------------------------------------- fp32 -> bf16 convert
__global__ __launch_bounds__(256) void k_cvt(const floatx4* __restrict__ src,
                                             short4v* __restrict__ dst, int n4) {
    int i = blockIdx.x * 256 + threadIdx.x;
    if (i < n4) {
        floatx4 v = src[i];
        short4v o;
        o[0] = (short)f2bf(v[0]);
        o[1] = (short)f2bf(v[1]);
        o[2] = (short)f2bf(v[2]);
        o[3] = (short)f2bf(v[3]);
        dst[i] = o;
    }
}

// ---------------------------------------------------------------- fp32 transpose -> bf16
__global__ __launch_bounds__(256) void k_transpose_cvt(const float* __restrict__ src,
                                                       ushort_t* __restrict__ dst, int R, int C) {
    __shared__ float t[32][33];
    int tx = threadIdx.x & 31, ty = threadIdx.x >> 5;
    int r0 = blockIdx.y * 32, c0 = blockIdx.x * 32;
    for (int y = ty; y < 32; y += 8) t[y][tx] = src[(r0 + y) * C + c0 + tx];
    __syncthreads();
    for (int y = ty; y < 32; y += 8) dst[(c0 + y) * R + r0 + tx] = f2bf(t[tx][y]);
}

// ---------------------------------------------------------------- K1: qkv = x @ w_qkv
__global__ __launch_bounds__(256, 3) void k_qkv(const ushort_t* __restrict__ x,
                                                const ushort_t* __restrict__ wt,
                                                ushort_t* __restrict__ qs,
                                                ushort_t* __restrict__ ks,
                                                ushort_t* __restrict__ vt) {
    __shared__ __align__(16) ushort_t st[9216];  // 128*72 (q/k) or 64*136 (vT)
    const int tid = threadIdx.x, lane = tid & 63, wv = tid >> 6;
    const int col = lane & 15, quad = lane >> 4;
    const int which = blockIdx.x >> 3, hh = blockIdx.x & 7;
    const int c0 = blockIdx.x * 64;
    const int absrow0 = blockIdx.y * 128;
    const int bb = blockIdx.y >> 4, n0 = (blockIdx.y & 15) * 128;
    const int hidx = bb * 8 + hh;
    const int row0 = absrow0 + wv * 32;
    floatx4 acc[2][4];
#pragma unroll
    for (int i = 0; i < 2; i++)
#pragma unroll
        for (int j = 0; j < 4; j++) acc[i][j] = (floatx4){0.f, 0.f, 0.f, 0.f};
    for (int k0 = 0; k0 < 512; k0 += 32) {
        const int ko = k0 + quad * 8;
        short8 a0 = *(const short8*)&x[(row0 + col) * 512 + ko];
        short8 a1 = *(const short8*)&x[(row0 + 16 + col) * 512 + ko];
        short8 b0 = *(const short8*)&wt[(c0 + col) * 512 + ko];
        short8 b1 = *(const short8*)&wt[(c0 + 16 + col) * 512 + ko];
        short8 b2 = *(const short8*)&wt[(c0 + 32 + col) * 512 + ko];
        short8 b3 = *(const short8*)&wt[(c0 + 48 + col) * 512 + ko];
        acc[0][0] = MFMA16(a0, b0, acc[0][0]);
        acc[0][1] = MFMA16(a0, b1, acc[0][1]);
        acc[0][2] = MFMA16(a0, b2, acc[0][2]);
        acc[0][3] = MFMA16(a0, b3, acc[0][3]);
        acc[1][0] = MFMA16(a1, b0, acc[1][0]);
        acc[1][1] = MFMA16(a1, b1, acc[1][1]);
        acc[1][2] = MFMA16(a1, b2, acc[1][2]);
        acc[1][3] = MFMA16(a1, b3, acc[1][3]);
    }
    const float qscale = (which == 0) ? 0.125f : 1.0f;  // fold SCALE into q
#pragma unroll
    for (int i = 0; i < 2; i++)
#pragma unroll
        for (int j = 0; j < 4; j++)
#pragma unroll
            for (int r = 0; r < 4; r++) {
                int il = wv * 32 + i * 16 + quad * 4 + r;  // 0..127
                int cl = j * 16 + col;                     // 0..63
                ushort_t hv = f2bf(acc[i][j][r] * qscale);
                if (which == 2) st[cl * 136 + il] = hv;  // transposed: [d][n]
                else            st[il * 72 + cl] = hv;   // [n][d]
            }
    __syncthreads();
    if (which < 2) {
        ushort_t* dst = (which == 0) ? qs : ks;
#pragma unroll
        for (int s = tid; s < 1024; s += 256) {
            int rr = s >> 3, dc = (s & 7) * 8;
            *(short8*)&dst[(hidx * 2048 + n0 + rr) * 64 + dc] = *(const short8*)&st[rr * 72 + dc];
        }
    } else {
#pragma unroll
        for (int s = tid; s < 1024; s += 256) {
            int d = s >> 4, nc = (s & 15) * 8;
            *(short8*)&vt[(hidx * 64 + d) * 2048 + n0 + nc] = *(const short8*)&st[d * 136 + nc];
        }
    }
}

// ---------------------------------------------------------------- K2: merged fused attention
// Block = (b, 16 query rows), 8 waves. Pass 1: barrier-free l_g (each wave owns a
// private 256-j span). One reduce. Pass 2: 256-j mega-tiles — waves mix their own
// 32-j slice (premix+exp*linv+postmix -> amix), ONE barrier, wave-e PV over the
// full tile, barrier. Epilogue: fused output projection (no atomics).
__global__ __launch_bounds__(512, 2) void k_attn(const ushort_t* __restrict__ qs,
                                                 const ushort_t* __restrict__ ks,
                                                 const ushort_t* __restrict__ vt,
                                                 const float* __restrict__ w_pre,
                                                 const float* __restrict__ w_post,
                                                 const ushort_t* __restrict__ wot,
                                                 const float* __restrict__ bias,
                                                 float* __restrict__ out) {
    __shared__ __align__(16) ushort_t qlds[8 * 16 * 72];   // 18.4 KB
    __shared__ __align__(16) ushort_t amix[8 * 16 * 264];  // 67.6 KB (aliased as oline later)
    __shared__ float lred[8][8][16];                       // 4 KB
    __shared__ float linv[8][16];
    const int tid = threadIdx.x, lane = tid & 63, wv = tid >> 6;
    const int col = lane & 15, quad = lane >> 4;
    const int b = blockIdx.y, n0 = blockIdx.x * 16;
    const int e = wv;  // wave's output head in PV/projection

    for (int c = tid; c < 1024; c += 512) {
        int hh = c >> 7, rem = c & 127, ii = rem >> 3, dc = (rem & 7) * 8;
        *(short8*)&qlds[(hh * 16 + ii) * 72 + dc] =
            *(const short8*)&qs[((b * 8 + hh) * 2048 + n0 + ii) * 64 + dc];
    }
    __syncthreads();

    // ================= pass 1: l_g partials, fully barrier-free per wave
    float Lacc[8][4];
#pragma unroll
    for (int g = 0; g < 8; g++)
#pragma unroll
        for (int r = 0; r < 4; r++) Lacc[g][r] = 0.f;
    for (int t = 0; t < 16; t++) {
        const int jw = wv * 256 + t * 16;
        floatx4 S[8];
#pragma unroll
        for (int h = 0; h < 8; h++) {
            const ushort_t* qb = &qlds[(h * 16 + col) * 72 + quad * 8];
            short8 a0 = *(const short8*)&qb[0];
            short8 a1 = *(const short8*)&qb[32];
            const ushort_t* kb = &ks[((b * 8 + h) * 2048 + jw + col) * 64 + quad * 8];
            short8 b0 = *(const short8*)&kb[0];
            short8 b1 = *(const short8*)&kb[32];
            floatx4 a = (floatx4){0.f, 0.f, 0.f, 0.f};
            a = MFMA16(a0, b0, a);
            a = MFMA16(a1, b1, a);
            S[h] = a;
        }
#pragma unroll
        for (int g = 0; g < 8; g++)
#pragma unroll
            for (int r = 0; r < 4; r++) {
                float s = 0.f;
#pragma unroll
                for (int h = 0; h < 8; h++) s = fmaf(w_pre[g * 8 + h], S[h][r], s);
                Lacc[g][r] += __expf(s);
            }
    }
#pragma unroll
    for (int g = 0; g < 8; g++)
#pragma unroll
        for (int r = 0; r < 4; r++) {
            float v = Lacc[g][r];
            v += __shfl_xor(v, 1, 64);
            v += __shfl_xor(v, 2, 64);
            v += __shfl_xor(v, 4, 64);
            v += __shfl_xor(v, 8, 64);
            if (col == 0) lred[wv][g][quad * 4 + r] = v;
        }
    __syncthreads();
    if (tid < 128) {
        int g = tid >> 4, ii = tid & 15;
        float l = 0.f;
#pragma unroll
        for (int w2 = 0; w2 < 8; w2++) l += lred[w2][g][ii];
        linv[g][ii] = 1.0f / l;
    }
    __syncthreads();
    float lr[8][4];
#pragma unroll
    for (int g = 0; g < 8; g++)
#pragma unroll
        for (int r = 0; r < 4; r++) lr[g][r] = linv[g][quad * 4 + r];

    // ================= pass 2: 256-j mega-tiles
    floatx4 O[4];
#pragma unroll
    for (int nt = 0; nt < 4; nt++) O[nt] = (floatx4){0.f, 0.f, 0.f, 0.f};

    for (int tile = 0; tile < 8; tile++) {
        const int j0t = tile * 256;
        // ---- mix phase: this wave's 32-j slice (2 independent subtiles)
#pragma unroll
        for (int sub = 0; sub < 2; sub++) {
            const int jw = j0t + wv * 32 + sub * 16;
            floatx4 S[8];
#pragma unroll
            for (int h = 0; h < 8; h++) {
                const ushort_t* qb = &qlds[(h * 16 + col) * 72 + quad * 8];
                short8 a0 = *(const short8*)&qb[0];
                short8 a1 = *(const short8*)&qb[32];
                const ushort_t* kb = &ks[((b * 8 + h) * 2048 + jw + col) * 64 + quad * 8];
                short8 b0 = *(const short8*)&kb[0];
                short8 b1 = *(const short8*)&kb[32];
                floatx4 a = (floatx4){0.f, 0.f, 0.f, 0.f};
                a = MFMA16(a0, b0, a);
                a = MFMA16(a1, b1, a);
                S[h] = a;
            }
            float P[8][4];
#pragma unroll
            for (int g = 0; g < 8; g++)
#pragma unroll
                for (int r = 0; r < 4; r++) {
                    float s = 0.f;
#pragma unroll
                    for (int h = 0; h < 8; h++) s = fmaf(w_pre[g * 8 + h], S[h][r], s);
                    P[g][r] = __expf(s) * lr[g][r];
                }
#pragma unroll
            for (int e2 = 0; e2 < 8; e2++)
#pragma unroll
                for (int r = 0; r < 4; r++) {
                    float a = 0.f;
#pragma unroll
                    for (int g = 0; g < 8; g++) a = fmaf(w_post[e2 * 8 + g], P[g][r], a);
                    amix[(e2 * 16 + quad * 4 + r) * 264 + wv * 32 + sub * 16 + col] = f2bf(a);
                }
        }
        __syncthreads();
        // ---- PV phase: wave e over the full 256-j tile
#pragma unroll
        for (int k2 = 0; k2 < 8; k2++) {
            short8 af = *(const short8*)&amix[(e * 16 + col) * 264 + k2 * 32 + quad * 8];
#pragma unroll
            for (int nt = 0; nt < 4; nt++) {
                short8 bf = *(const short8*)&vt[((b * 8 + e) * 64 + nt * 16 + col) * 2048 + j0t +
                                                k2 * 32 + quad * 8];
                O[nt] = MFMA16(af, bf, O[nt]);
            }
        }
        __syncthreads();
    }
    // ---- stage attention-out rows (16 x 512), aliasing amix
    ushort_t* oline = amix;
#pragma unroll
    for (int nt = 0; nt < 4; nt++)
#pragma unroll
        for (int r = 0; r < 4; r++)
            oline[(quad * 4 + r) * 520 + e * 64 + nt * 16 + col] = f2bf(O[nt][r]);
    __syncthreads();
    // ---- fused output projection
#pragma unroll
    for (int nt = 0; nt < 4; nt++) {
        floatx4 acc = (floatx4){0.f, 0.f, 0.f, 0.f};
        const int c = wv * 64 + nt * 16 + col;
#pragma unroll
        for (int k2 = 0; k2 < 16; k2++) {
            short8 af = *(const short8*)&oline[col * 520 + k2 * 32 + quad * 8];
            short8 bf = *(const short8*)&wot[c * 512 + k2 * 32 + quad * 8];
            acc = MFMA16(af, bf, acc);
        }
        float bz = bias[c];
#pragma unroll
        for (int r = 0; r < 4; r++)
            out[(b * 2048 + n0 + quad * 4 + r) * 512 + c] = acc[r] + bz;
    }
}

// ---------------------------------------------------------------- launch
extern "C" void kernel_launch(void* const* d_in, const int* in_sizes, int n_in,
                              void* d_out, int out_size, void* d_ws, size_t ws_size,
                              hipStream_t stream) {
    const float* x = (const float*)d_in[0];
    const float* w_qkv = (const float*)d_in[1];
    const float* w_pre = (const float*)d_in[2];
    const float* w_post = (const float*)d_in[3];
    const float* w_out = (const float*)d_in[4];
    const float* b_out = (const float*)d_in[5];
    char* ws = (char*)d_ws;
    ushort_t* qs = (ushort_t*)(ws);                            // 4 MB  [b,h,n,d] (pre-scaled)
    ushort_t* ks = (ushort_t*)(ws + (4u << 20));               // 4 MB  [b,h,n,d]
    ushort_t* vt = (ushort_t*)(ws + (8u << 20));               // 4 MB  [b,h,d,n]
    ushort_t* xb = (ushort_t*)(ws + (12u << 20));              // 4 MB  x in bf16
    ushort_t* wt = (ushort_t*)(ws + (16u << 20));              // 1.5 MB w_qkv^T bf16
    ushort_t* wot = (ushort_t*)(ws + (16u << 20) + 1572864u);  // 0.5 MB w_out^T bf16
    float* out = (float*)d_out;

    k_cvt<<<dim3(2048), dim3(256), 0, stream>>>((const floatx4*)x, (short4v*)xb, 524288);
    k_transpose_cvt<<<dim3(48, 16), dim3(256), 0, stream>>>(w_qkv, wt, 512, 1536);
    k_transpose_cvt<<<dim3(16, 16), dim3(256), 0, stream>>>(w_out, wot, 512, 512);
    k_qkv<<<dim3(24, 32), dim3(256), 0, stream>>>(xb, wt, qs, ks, vt);
    k_attn<<<dim3(128, 2), dim3(512), 0, stream>>>(qs, ks, vt, w_pre, w_post, wot, b_out, out);
}

// Round 8
// 321.317 us; speedup vs baseline: 1.1813x; 1.0733x over previous
//
#include <hip/hip_runtime.h>
#include <hip/hip_bf16.h>

typedef unsigned short ushort_t;
typedef __attribute__((ext_vector_type(8))) short short8;
typedef __attribute__((ext_vector_type(4))) short short4v;
typedef __attribute__((ext_vector_type(4))) float floatx4;
typedef __attribute__((ext_vector_type(2))) float floatx2;

#define MFMA16(a, b, c) __builtin_amdgcn_mfma_f32_16x16x32_bf16(a, b, c, 0, 0, 0)

__device__ __forceinline__ float bf2f(ushort_t u) {
    unsigned int v = ((unsigned int)u) << 16;
    return __int_as_float((int)v);
}
__device__ __forceinline__ ushort_t f2bf(float f) {
    unsigned int x = (unsigned int)__float_as_int(f);
    unsigned int r = (x + 0x7FFFu + ((x >> 16) & 1u)) >> 16;
    return (ushort_t)r;
}

// ---------------------------------------------------------------- fp32 -> bf16 convert
__global__ __launch_bounds__(256) void k_cvt(const floatx4* __restrict__ src,
                                             short4v* __restrict__ dst, int n4) {
    int i = blockIdx.x * 256 + threadIdx.x;
    if (i < n4) {
        floatx4 v = src[i];
        short4v o;
        o[0] = (short)f2bf(v[0]);
        o[1] = (short)f2bf(v[1]);
        o[2] = (short)f2bf(v[2]);
        o[3] = (short)f2bf(v[3]);
        dst[i] = o;
    }
}

// ---------------------------------------------------------------- fp32 transpose -> bf16
__global__ __launch_bounds__(256) void k_transpose_cvt(const float* __restrict__ src,
                                                       ushort_t* __restrict__ dst, int R, int C) {
    __shared__ float t[32][33];
    int tx = threadIdx.x & 31, ty = threadIdx.x >> 5;
    int r0 = blockIdx.y * 32, c0 = blockIdx.x * 32;
    for (int y = ty; y < 32; y += 8) t[y][tx] = src[(r0 + y) * C + c0 + tx];
    __syncthreads();
    for (int y = ty; y < 32; y += 8) dst[(c0 + y) * R + r0 + tx] = f2bf(t[tx][y]);
}

// ---------------------------------------------------------------- K1: qkv = x @ w_qkv
__global__ __launch_bounds__(256, 3) void k_qkv(const ushort_t* __restrict__ x,
                                                const ushort_t* __restrict__ wt,
                                                ushort_t* __restrict__ qs,
                                                ushort_t* __restrict__ ks,
                                                ushort_t* __restrict__ vt) {
    __shared__ __align__(16) ushort_t st[9216];  // 128*72 (q/k) or 64*136 (vT)
    const int tid = threadIdx.x, lane = tid & 63, wv = tid >> 6;
    const int col = lane & 15, quad = lane >> 4;
    const int which = blockIdx.x >> 3, hh = blockIdx.x & 7;
    const int c0 = blockIdx.x * 64;
    const int absrow0 = blockIdx.y * 128;
    const int bb = blockIdx.y >> 4, n0 = (blockIdx.y & 15) * 128;
    const int hidx = bb * 8 + hh;
    const int row0 = absrow0 + wv * 32;
    floatx4 acc[2][4];
#pragma unroll
    for (int i = 0; i < 2; i++)
#pragma unroll
        for (int j = 0; j < 4; j++) acc[i][j] = (floatx4){0.f, 0.f, 0.f, 0.f};
    for (int k0 = 0; k0 < 512; k0 += 32) {
        const int ko = k0 + quad * 8;
        short8 a0 = *(const short8*)&x[(row0 + col) * 512 + ko];
        short8 a1 = *(const short8*)&x[(row0 + 16 + col) * 512 + ko];
        short8 b0 = *(const short8*)&wt[(c0 + col) * 512 + ko];
        short8 b1 = *(const short8*)&wt[(c0 + 16 + col) * 512 + ko];
        short8 b2 = *(const short8*)&wt[(c0 + 32 + col) * 512 + ko];
        short8 b3 = *(const short8*)&wt[(c0 + 48 + col) * 512 + ko];
        acc[0][0] = MFMA16(a0, b0, acc[0][0]);
        acc[0][1] = MFMA16(a0, b1, acc[0][1]);
        acc[0][2] = MFMA16(a0, b2, acc[0][2]);
        acc[0][3] = MFMA16(a0, b3, acc[0][3]);
        acc[1][0] = MFMA16(a1, b0, acc[1][0]);
        acc[1][1] = MFMA16(a1, b1, acc[1][1]);
        acc[1][2] = MFMA16(a1, b2, acc[1][2]);
        acc[1][3] = MFMA16(a1, b3, acc[1][3]);
    }
    const float qscale = (which == 0) ? 0.125f : 1.0f;  // fold SCALE into q
#pragma unroll
    for (int i = 0; i < 2; i++)
#pragma unroll
        for (int j = 0; j < 4; j++)
#pragma unroll
            for (int r = 0; r < 4; r++) {
                int il = wv * 32 + i * 16 + quad * 4 + r;  // 0..127
                int cl = j * 16 + col;                     // 0..63
                ushort_t hv = f2bf(acc[i][j][r] * qscale);
                if (which == 2) st[cl * 136 + il] = hv;  // transposed: [d][n]
                else            st[il * 72 + cl] = hv;   // [n][d]
            }
    __syncthreads();
    if (which < 2) {
        ushort_t* dst = (which == 0) ? qs : ks;
#pragma unroll
        for (int s = tid; s < 1024; s += 256) {
            int rr = s >> 3, dc = (s & 7) * 8;
            *(short8*)&dst[(hidx * 2048 + n0 + rr) * 64 + dc] = *(const short8*)&st[rr * 72 + dc];
        }
    } else {
#pragma unroll
        for (int s = tid; s < 1024; s += 256) {
            int d = s >> 4, nc = (s & 15) * 8;
            *(short8*)&vt[(hidx * 64 + d) * 2048 + n0 + nc] = *(const short8*)&st[d * 136 + nc];
        }
    }
}

// ---------------------------------------------------------------- K2: single-pass attention
// Deferred normalization (round-4 algebra, now at full 256-reg budget):
//   U_g = exp(premix(S)); Oa[g] += U_g @ V_e; Lacc[g] += U_g
//   epilogue: O_e = sum_g wq[e,g]/l_g * Oa[g]  -> fused projection.
// Hot loop touches ONLY w_pre (64 scalars -> SGPR-resident); no postmix in loop;
// premix packed (v_pk_fma_f32). One S+premix+exp sweep total (not two).
__global__ __launch_bounds__(512, 1) void k_attn(const ushort_t* __restrict__ qs,
                                                 const ushort_t* __restrict__ ks,
                                                 const ushort_t* __restrict__ vt,
                                                 const float* __restrict__ w_pre,
                                                 const float* __restrict__ w_post,
                                                 const ushort_t* __restrict__ wot,
                                                 const float* __restrict__ bias,
                                                 float* __restrict__ out) {
    __shared__ __align__(16) ushort_t qlds[8 * 16 * 72];   // 18.4 KB
    __shared__ __align__(16) ushort_t U[8 * 16 * 140];     // 35.8 KB (stride 140: conflict-free)
    __shared__ float lred[8][8][16];                       // 4 KB
    __shared__ float linv[8][16];
    const int tid = threadIdx.x, lane = tid & 63, wv = tid >> 6;
    const int col = lane & 15, quad = lane >> 4;
    const int b = blockIdx.y, n0 = blockIdx.x * 16;
    const int e = wv;  // wave's output head

    for (int c = tid; c < 1024; c += 512) {
        int hh = c >> 7, rem = c & 127, ii = rem >> 3, dc = (rem & 7) * 8;
        *(short8*)&qlds[(hh * 16 + ii) * 72 + dc] =
            *(const short8*)&qs[((b * 8 + hh) * 2048 + n0 + ii) * 64 + dc];
    }
    __syncthreads();

    floatx4 Oa[8][4];
    float Lacc[8][4];
#pragma unroll
    for (int g = 0; g < 8; g++) {
#pragma unroll
        for (int nt = 0; nt < 4; nt++) Oa[g][nt] = (floatx4){0.f, 0.f, 0.f, 0.f};
#pragma unroll
        for (int r = 0; r < 4; r++) Lacc[g][r] = 0.f;
    }

    for (int tile = 0; tile < 16; tile++) {
        const int j0 = tile * 128;
        const int jw = j0 + wv * 16;
        // ---- S for all 8 input heads (this wave's 16-j slice)
        floatx4 S[8];
#pragma unroll
        for (int h = 0; h < 8; h++) {
            const ushort_t* qb = &qlds[(h * 16 + col) * 72 + quad * 8];
            short8 a0 = *(const short8*)&qb[0];
            short8 a1 = *(const short8*)&qb[32];
            const ushort_t* kb = &ks[((b * 8 + h) * 2048 + jw + col) * 64 + quad * 8];
            short8 b0 = *(const short8*)&kb[0];
            short8 b1 = *(const short8*)&kb[32];
            floatx4 a = (floatx4){0.f, 0.f, 0.f, 0.f};
            a = MFMA16(a0, b0, a);
            a = MFMA16(a1, b1, a);
            S[h] = a;
        }
        // ---- premix (packed, w_pre only) + exp, U write (A-layout), Lacc
#pragma unroll
        for (int g = 0; g < 8; g++)
#pragma unroll
            for (int r2 = 0; r2 < 2; r2++) {
                floatx2 s = (floatx2){0.f, 0.f};
#pragma unroll
                for (int h = 0; h < 8; h++) {
                    floatx2 sv = (floatx2){S[h][2 * r2], S[h][2 * r2 + 1]};
                    s += sv * w_pre[g * 8 + h];  // v_pk_fma_f32
                }
                float u0 = __expf(s.x), u1 = __expf(s.y);
                Lacc[g][2 * r2] += u0;
                Lacc[g][2 * r2 + 1] += u1;
                U[(g * 16 + quad * 4 + 2 * r2) * 140 + wv * 16 + col] = f2bf(u0);
                U[(g * 16 + quad * 4 + 2 * r2 + 1) * 140 + wv * 16 + col] = f2bf(u1);
            }
        __syncthreads();
        // ---- PV: wave e, ALL g, over this 128-j tile (postmix deferred)
#pragma unroll
        for (int k2 = 0; k2 < 4; k2++) {
            short8 bf[4];
#pragma unroll
            for (int nt = 0; nt < 4; nt++)
                bf[nt] = *(const short8*)&vt[((b * 8 + e) * 64 + nt * 16 + col) * 2048 + j0 +
                                             k2 * 32 + quad * 8];
#pragma unroll
            for (int g = 0; g < 8; g++) {
                short8 af = *(const short8*)&U[(g * 16 + col) * 140 + k2 * 32 + quad * 8];
#pragma unroll
                for (int nt = 0; nt < 4; nt++) Oa[g][nt] = MFMA16(af, bf[nt], Oa[g][nt]);
            }
        }
        __syncthreads();
    }

    // ---- reduce l across 16 cols in-wave, then across waves
#pragma unroll
    for (int g = 0; g < 8; g++)
#pragma unroll
        for (int r = 0; r < 4; r++) {
            float v = Lacc[g][r];
            v += __shfl_xor(v, 1, 64);
            v += __shfl_xor(v, 2, 64);
            v += __shfl_xor(v, 4, 64);
            v += __shfl_xor(v, 8, 64);
            if (col == 0) lred[wv][g][quad * 4 + r] = v;
        }
    __syncthreads();
    if (tid < 128) {
        int g = tid >> 4, ii = tid & 15;
        float l = 0.f;
#pragma unroll
        for (int w2 = 0; w2 < 8; w2++) l += lred[w2][g][ii];
        linv[g][ii] = 1.0f / l;
    }
    __syncthreads();
    // ---- epilogue combine: O_e = sum_g wq[e,g]/l_g[i] * Oa[g]
    float coef[8][4];
#pragma unroll
    for (int g = 0; g < 8; g++) {
        float wqe = w_post[e * 8 + g];
#pragma unroll
        for (int r = 0; r < 4; r++) coef[g][r] = wqe * linv[g][quad * 4 + r];
    }
    ushort_t* oline = U;  // alias (needs 16.6 KB of U's 35.8 KB)
#pragma unroll
    for (int nt = 0; nt < 4; nt++)
#pragma unroll
        for (int r = 0; r < 4; r++) {
            float o = 0.f;
#pragma unroll
            for (int g = 0; g < 8; g++) o = fmaf(coef[g][r], Oa[g][nt][r], o);
            oline[(quad * 4 + r) * 520 + e * 64 + nt * 16 + col] = f2bf(o);
        }
    __syncthreads();
    // ---- fused output projection
#pragma unroll
    for (int nt = 0; nt < 4; nt++) {
        floatx4 acc = (floatx4){0.f, 0.f, 0.f, 0.f};
        const int c = wv * 64 + nt * 16 + col;
#pragma unroll
        for (int k2 = 0; k2 < 16; k2++) {
            short8 af = *(const short8*)&oline[col * 520 + k2 * 32 + quad * 8];
            short8 bf = *(const short8*)&wot[c * 512 + k2 * 32 + quad * 8];
            acc = MFMA16(af, bf, acc);
        }
        float bz = bias[c];
#pragma unroll
        for (int r = 0; r < 4; r++)
            out[(b * 2048 + n0 + quad * 4 + r) * 512 + c] = acc[r] + bz;
    }
}

// ---------------------------------------------------------------- launch
extern "C" void kernel_launch(void* const* d_in, const int* in_sizes, int n_in,
                              void* d_out, int out_size, void* d_ws, size_t ws_size,
                              hipStream_t stream) {
    const float* x = (const float*)d_in[0];
    const float* w_qkv = (const float*)d_in[1];
    const float* w_pre = (const float*)d_in[2];
    const float* w_post = (const float*)d_in[3];
    const float* w_out = (const float*)d_in[4];
    const float* b_out = (const float*)d_in[5];
    char* ws = (char*)d_ws;
    ushort_t* qs = (ushort_t*)(ws);                            // 4 MB  [b,h,n,d] (pre-scaled)
    ushort_t* ks = (ushort_t*)(ws + (4u << 20));               // 4 MB  [b,h,n,d]
    ushort_t* vt = (ushort_t*)(ws + (8u << 20));               // 4 MB  [b,h,d,n]
    ushort_t* xb = (ushort_t*)(ws + (12u << 20));              // 4 MB  x in bf16
    ushort_t* wt = (ushort_t*)(ws + (16u << 20));              // 1.5 MB w_qkv^T bf16
    ushort_t* wot = (ushort_t*)(ws + (16u << 20) + 1572864u);  // 0.5 MB w_out^T bf16
    float* out = (float*)d_out;

    k_cvt<<<dim3(2048), dim3(256), 0, stream>>>((const floatx4*)x, (short4v*)xb, 524288);
    k_transpose_cvt<<<dim3(48, 16), dim3(256), 0, stream>>>(w_qkv, wt, 512, 1536);
    k_transpose_cvt<<<dim3(16, 16), dim3(256), 0, stream>>>(w_out, wot, 512, 512);
    k_qkv<<<dim3(24, 32), dim3(256), 0, stream>>>(xb, wt, qs, ks, vt);
    k_attn<<<dim3(128, 2), dim3(512), 0, stream>>>(qs, ks, vt, w_pre, w_post, wot, b_out, out);
}